// Round 1
// 204.415 us; speedup vs baseline: 1.0485x; 1.0485x over previous
//
#include <hip/hip_runtime.h>
#include <math.h>
#include <stdint.h>

#define NTOT   8192
#define HALF_N 4096
#define DIM    512
#define INV_T  14.2857142857142857f   // 1/0.07

using s16x8 = __attribute__((ext_vector_type(8))) short;
using f32x4 = __attribute__((ext_vector_type(4))) float;

// Scratch in static device globals (fully rewritten every call; no d_ws use).
__device__ unsigned short g_fnb[NTOT * DIM];   // normalized bf16 matrix, 8 MB
__device__ float g_pos[NTOT];
__device__ float g_sumexp[NTOT];
__device__ int   g_cnt[NTOT];

__device__ __forceinline__ float bf2f(unsigned short u) {
  union { unsigned int i; float f; } v; v.i = ((unsigned int)u) << 16; return v.f;
}
__device__ __forceinline__ unsigned short f2bf(float x) {
  union { float f; unsigned int i; } v; v.f = x;
  unsigned int u = v.i;
  return (unsigned short)((u + 0x7FFFu + ((u >> 16) & 1u)) >> 16);
}

// async global->LDS, 16 B per lane. LDS dest is wave-uniform base + lane*16.
__device__ __forceinline__ void gload16(const unsigned short* g, unsigned short* l) {
  __builtin_amdgcn_global_load_lds(
      (const __attribute__((address_space(1))) unsigned int*)g,
      (__attribute__((address_space(3))) unsigned int*)l, 16, 0, 0);
}

// ---------------- kernel 1: normalize pairs -> bf16, pos, zero stats ----------------
// 256 threads = 2 pairs. Waves (0,1) handle pair 2B, waves (2,3) pair 2B+1.
// Within a pair: first wave = row b (f1), second wave = row b+4096 (f2).
__global__ __launch_bounds__(256) void knorm(const float* __restrict__ f1,
                                             const float* __restrict__ f2) {
  const int tid  = threadIdx.x;
  const int wv   = tid >> 6;
  const int pi   = wv >> 1;            // pair within block
  const int half = wv & 1;             // 0: f1 row, 1: f2 row
  const int lane = tid & 63;
  const int b    = blockIdx.x * 2 + pi;
  const int row  = b + half * HALF_N;

  if (tid < 4) {                       // zero the 4 stat rows this block owns
    const int r = blockIdx.x * 2 + (tid & 1) + (tid >> 1) * HALF_N;
    g_sumexp[r] = 0.f; g_cnt[r] = 0;
  }

  const float* src = (half == 0) ? (f1 + (size_t)b * DIM) : (f2 + (size_t)b * DIM);
  float4 v0 = ((const float4*)src)[lane];
  float4 v1 = ((const float4*)src)[lane + 64];
  float ss = v0.x*v0.x + v0.y*v0.y + v0.z*v0.z + v0.w*v0.w
           + v1.x*v1.x + v1.y*v1.y + v1.z*v1.z + v1.w*v1.w;
  #pragma unroll
  for (int o = 32; o >= 1; o >>= 1) ss += __shfl_xor(ss, o, 64);
  const float sc = 1.0f / fmaxf(sqrtf(ss), 1e-8f);
  ushort4 h0, h1;
  h0.x = f2bf(v0.x * sc); h0.y = f2bf(v0.y * sc);
  h0.z = f2bf(v0.z * sc); h0.w = f2bf(v0.w * sc);
  h1.x = f2bf(v1.x * sc); h1.y = f2bf(v1.y * sc);
  h1.z = f2bf(v1.z * sc); h1.w = f2bf(v1.w * sc);
  ushort4* dst = (ushort4*)(g_fnb + (size_t)row * DIM);
  dst[lane]      = h0;
  dst[lane + 64] = h1;

  // pos[b] = <fn_b, fn_{b+4096}> on the same bf16 values the GEMM uses
  __shared__ ushort4 sh[2][64][2];
  if (half == 1) { sh[pi][lane][0] = h0; sh[pi][lane][1] = h1; }
  __syncthreads();
  if (half == 0) {
    const ushort4 p0 = sh[pi][lane][0], p1 = sh[pi][lane][1];
    float s = bf2f(h0.x)*bf2f(p0.x) + bf2f(h0.y)*bf2f(p0.y)
            + bf2f(h0.z)*bf2f(p0.z) + bf2f(h0.w)*bf2f(p0.w)
            + bf2f(h1.x)*bf2f(p1.x) + bf2f(h1.y)*bf2f(p1.y)
            + bf2f(h1.z)*bf2f(p1.z) + bf2f(h1.w)*bf2f(p1.w);
    #pragma unroll
    for (int o = 32; o >= 1; o >>= 1) s += __shfl_xor(s, o, 64);
    if (lane == 0) { g_pos[b] = s; g_pos[b + HALF_N] = s; }
  }
}

// ---------------- kernel 2: symmetric fused GEMM + row/col reductions ----------------
// Upper-triangle blocks only (bi <= bj), 2080 blocks. Off-diagonal tiles feed
// row stats (i) AND col stats (j); diagonal blocks skip B staging (B == A).
//
// R1 (this session): staging via global_load_lds (m151: 646->874 TF at this
// exact 128^2/BK=64 shape vs reg-staging). LDS destination must be LINEAR
// (wave-uniform base + lane*16, m104/m108), so the XOR bank swizzle moves to
// the per-lane GLOBAL source address (rule #21: linear dest + inverse-swz
// source + swz read; XOR is an involution so source swz == read swz).
// This deletes 8 ds_write_b128 + the mid-loop vmcnt(0) drain per K-step and
// frees the 8 int4 prefetch VGPRs -> __launch_bounds__(256,4): 4 blocks/CU
// (prev 3) to hide the per-iteration L2/LLC staging latency with more
// cross-block overlap. acc(64) + frags(32) + addr ~= 110 < 128 unified regs.
__global__ __launch_bounds__(256, 4) void kmain() {
  __shared__ __align__(16) unsigned short As[128 * 64];
  __shared__ __align__(16) unsigned short Bs[128 * 64];

  // triangular decode: blockIdx -> (bi, bj), bi <= bj
  int t = blockIdx.x;
  int bi = 0, rem = 64;
  while (t >= rem) { t -= rem; --rem; ++bi; }
  const int bj = bi + t;
  const bool offdiag = (bi != bj);
  const int i0 = bi * 128, j0 = bj * 128;

  const int tid  = threadIdx.x;
  const int lane = tid & 63;
  const int w    = tid >> 6;
  const int wr   = (w >> 1) * 64;   // wave row base
  const int wc   = (w & 1) * 64;    // wave col base
  const int lrow = lane & 15;
  const int lq   = lane >> 4;

  // staging: wave w covers tile rows [w*32, w*32+32) in 4 chunks of 8 rows
  // (1 KB per gload16 call). Lane l -> LDS bytes chunk_base + l*16, i.e.
  // row = 8q + (l>>3), physical col-block p = l&7. That slot must hold
  // logical col-block p ^ (row&7)  (row&7 == l>>3 here).
  const int rsub = lane >> 3;               // row within 8-row chunk
  const int lcb  = (lane & 7) ^ rsub;       // inverse-swizzled source col block
  const unsigned short* Ag = g_fnb + (size_t)(i0 + w * 32 + rsub) * DIM + lcb * 8;
  const unsigned short* Bg = g_fnb + (size_t)(j0 + w * 32 + rsub) * DIM + lcb * 8;
  unsigned short* Al = &As[w * 32 * 64];    // wave-uniform LDS base
  unsigned short* Bl = &Bs[w * 32 * 64];

  f32x4 acc[4][4];
  #pragma unroll
  for (int a = 0; a < 4; ++a)
    #pragma unroll
    for (int bb = 0; bb < 4; ++bb) { acc[a][bb][0]=0.f; acc[a][bb][1]=0.f; acc[a][bb][2]=0.f; acc[a][bb][3]=0.f; }

  const unsigned short* Bls = offdiag ? (const unsigned short*)Bs
                                      : (const unsigned short*)As;

  for (int kt = 0; kt < 8; ++kt) {
    __syncthreads();                       // prev compute done, LDS reusable
    const int kb = kt * 64;
    #pragma unroll
    for (int q = 0; q < 4; ++q) {
      gload16(Ag + (size_t)(q * 8) * DIM + kb, Al + q * 512);
      if (offdiag) gload16(Bg + (size_t)(q * 8) * DIM + kb, Bl + q * 512);
    }
    __syncthreads();                       // vmcnt(0) drains here -> tile kt visible

    #pragma unroll
    for (int kk = 0; kk < 2; ++kk) {
      s16x8 af[4], bf[4];
      #pragma unroll
      for (int mi = 0; mi < 4; ++mi) {
        const int r = wr + mi * 16 + lrow;
        af[mi] = *(const s16x8*)(&As[r * 64 + (((kk * 4 + lq) ^ (lrow & 7)) * 8)]);
      }
      #pragma unroll
      for (int ni = 0; ni < 4; ++ni) {
        const int r = wc + ni * 16 + lrow;
        bf[ni] = *(const s16x8*)(&Bls[r * 64 + (((kk * 4 + lq) ^ (lrow & 7)) * 8)]);
      }
      #pragma unroll
      for (int mi = 0; mi < 4; ++mi)
        #pragma unroll
        for (int ni = 0; ni < 4; ++ni)
          acc[mi][ni] = __builtin_amdgcn_mfma_f32_16x16x32_bf16(af[mi], bf[ni], acc[mi][ni], 0, 0, 0);
    }
  }

  // ---- epilogue. C layout: col = lane&15 (+ni*16+wc), row = lq*4+reg (+mi*16+wr).
  // row side (always)
  #pragma unroll
  for (int mi = 0; mi < 4; ++mi) {
    #pragma unroll
    for (int r = 0; r < 4; ++r) {
      const int i  = i0 + wr + mi * 16 + lq * 4 + r;
      const float pv = g_pos[i];
      float s = 0.f; int c = 0;
      #pragma unroll
      for (int ni = 0; ni < 4; ++ni) {
        const int j = j0 + wc + ni * 16 + lrow;
        const float v = acc[mi][ni][r];
        const float e = __expf(v * INV_T);
        const bool diag = (j == i);
        s += diag ? 0.f : e;
        c += (!diag && (j != (i ^ HALF_N)) && (v > pv)) ? 1 : 0;
      }
      #pragma unroll
      for (int o = 1; o < 16; o <<= 1) {
        s += __shfl_xor(s, o, 64);
        c += __shfl_xor(c, o, 64);
      }
      if (lrow == 0) {
        atomicAdd(&g_sumexp[i], s);
        atomicAdd(&g_cnt[i], c);
      }
    }
  }

  // col side (off-diagonal only; i and j slabs disjoint -> j != i always)
  if (offdiag) {
    #pragma unroll
    for (int ni = 0; ni < 4; ++ni) {
      const int j  = j0 + wc + ni * 16 + lrow;
      const float pj = g_pos[j];
      float s = 0.f; int c = 0;
      #pragma unroll
      for (int mi = 0; mi < 4; ++mi) {
        #pragma unroll
        for (int r = 0; r < 4; ++r) {
          const int i = i0 + wr + mi * 16 + lq * 4 + r;
          const float v = acc[mi][ni][r];
          s += __expf(v * INV_T);
          c += ((i != (j ^ HALF_N)) && (v > pj)) ? 1 : 0;
        }
      }
      s += __shfl_xor(s, 16, 64); s += __shfl_xor(s, 32, 64);
      c += __shfl_xor(c, 16, 64); c += __shfl_xor(c, 32, 64);
      if (lq == 0) {
        atomicAdd(&g_sumexp[j], s);
        atomicAdd(&g_cnt[j], c);
      }
    }
  }
}

// ---------------- kernel 3: finalize the 4 scalars ----------------
__global__ __launch_bounds__(1024) void kfin(float* __restrict__ out) {
  const int tid = threadIdx.x;
  float nll = 0.f, t1 = 0.f, t5 = 0.f, mr = 0.f;
  for (int i = tid; i < NTOT; i += 1024) {
    nll += -g_pos[i] * INV_T + logf(g_sumexp[i]);
    const int c = g_cnt[i];
    t1 += (c == 0) ? 1.f : 0.f;
    t5 += (c < 5) ? 1.f : 0.f;
    mr += (float)c;
  }
  #pragma unroll
  for (int o = 32; o >= 1; o >>= 1) {
    nll += __shfl_xor(nll, o, 64);
    t1  += __shfl_xor(t1, o, 64);
    t5  += __shfl_xor(t5, o, 64);
    mr  += __shfl_xor(mr, o, 64);
  }
  __shared__ float red[16][4];
  const int wv = tid >> 6, lane = tid & 63;
  if (lane == 0) { red[wv][0] = nll; red[wv][1] = t1; red[wv][2] = t5; red[wv][3] = mr; }
  __syncthreads();
  if (tid == 0) {
    float a = 0.f, b = 0.f, c = 0.f, d = 0.f;
    for (int k = 0; k < 16; ++k) { a += red[k][0]; b += red[k][1]; c += red[k][2]; d += red[k][3]; }
    out[0] = a / (float)NTOT;
    out[1] = b / (float)NTOT;
    out[2] = c / (float)NTOT;
    out[3] = 1.f + d / (float)NTOT;
  }
}

extern "C" void kernel_launch(void* const* d_in, const int* in_sizes, int n_in,
                              void* d_out, int out_size, void* d_ws, size_t ws_size,
                              hipStream_t stream) {
  const float* f1 = (const float*)d_in[0];
  const float* f2 = (const float*)d_in[1];
  float* out = (float*)d_out;

  knorm<<<dim3(2048), dim3(256), 0, stream>>>(f1, f2);
  kmain<<<dim3(2080), dim3(256), 0, stream>>>();
  kfin <<<dim3(1),    dim3(1024), 0, stream>>>(out);
}